// Round 2
// baseline (246.923 us; speedup 1.0000x reference)
//
#include <hip/hip_runtime.h>

// Problem constants
#define NODES  116
#define HEADS  2
#define DH     116
#define HID    256
#define NGRAPH 512
#define NN     (NGRAPH*NODES)    // 59392
#define DEG    8
#define DOUT   (HEADS*DH)        // 232
#define RSTR   136               // parked-tile row stride (272B, 16B-aligned rows)

typedef short  s8v  __attribute__((ext_vector_type(8)));
typedef float  f4v  __attribute__((ext_vector_type(4)));

static __device__ __forceinline__ float bf2f(unsigned short u) {
    union { unsigned int i; float f; } c; c.i = ((unsigned int)u) << 16; return c.f;
}
static __device__ __forceinline__ unsigned short f2bf(float f) {
    union { float f; unsigned int u; } c; c.f = f;
    unsigned int u = c.u;
    unsigned int r = (u + 0x7FFFu + ((u >> 16) & 1u)) >> 16;   // RNE
    return (unsigned short)r;
}

#define GLD_LDS16(gptr, lptr) \
    __builtin_amdgcn_global_load_lds((const __attribute__((address_space(1))) void*)(gptr), \
                                     (__attribute__((address_space(3))) void*)(lptr), 16, 0, 0)

// ---------------------------------------------------------------------------
// P: wt bf16 [hd(2)][chunk(4)][kb(8)][quad(4)][n(128)][8k]; chunk = Wq,Wk,Wv,Ws
// columns hd*116..+116, transposed, zero-padded n>=116.  (round-0 verified)
// ---------------------------------------------------------------------------
__global__ __launch_bounds__(256) void prep_w(const float* __restrict__ Wq,
                                              const float* __restrict__ Wk,
                                              const float* __restrict__ Wv,
                                              const float* __restrict__ Ws,
                                              unsigned short* __restrict__ wt)
{
    unsigned int f = blockIdx.x * 256 + threadIdx.x;   // granule id < 32768
    unsigned int n    = f & 127;
    unsigned int quad = (f >> 7) & 3;
    unsigned int kb   = (f >> 9) & 7;
    unsigned int ch   = (f >> 12) & 3;
    unsigned int hd   = f >> 14;
    unsigned short o[8] = {0,0,0,0,0,0,0,0};
    if (n < NODES) {
        unsigned int col = hd * DH + n;
        unsigned int k   = kb * 32 + quad * 8;
        const float* W = (ch == 0) ? Wq : (ch == 1) ? Wk : (ch == 2) ? Wv : Ws;
        #pragma unroll
        for (int i = 0; i < 8; i++)
            o[i] = f2bf(W[(size_t)(k + i) * DOUT + col]);
    }
    *(uint4*)(wt + (size_t)f * 8) = *(const uint4*)o;
}

// ---------------------------------------------------------------------------
// K1: one block per GRAPH (both heads sequentially), 1024 threads = 16 waves.
//   Per head: double-buffered GEMM pipeline (stage(kb+1) issued BEFORE
//   compute(kb), ONE __syncthreads per k-step — compiler-fenced, race-proof)
//   -> park q,k -> S=QK^T + scatter -> zero W + park V^T (over ql) ->
//   softmax (in-place in scf) -> serial dense-W build -> W@V onto skip frags
//   -> h_proj park -> row sums into LDS ps[hd]; head0 h_proj spilled to hp
//   (bf16 compact 116 cols), head1 kept in LDS.
//   Tail: per-graph softmax pooling + f32 outputs (pool_k2 eliminated).
//   All arithmetic paths are the round-0 verified forms (scalar f2bf RNE,
//   equality scatter, serial dedup W-build).
// ---------------------------------------------------------------------------
__global__ __launch_bounds__(1024) void fused_all(
    const float* __restrict__ h,
    const unsigned short* __restrict__ wt,
    const int* __restrict__ eidx,
    unsigned short* __restrict__ hp,
    float* __restrict__ out_alpha,
    float* __restrict__ out_hw)
{
    __shared__ __align__(16) unsigned short stA[2*4096];    // 16,384 B (dbuf A)
    __shared__ __align__(16) unsigned short stB[2*16384];   // 65,536 B (dbuf B)
    __shared__ __align__(16) unsigned short ql[128*RSTR];   // 34,816 B (q -> v^T -> h_proj)
    __shared__ __align__(16) unsigned short kl[128*RSTR];   // 34,816 B (k -> dense W)
    __shared__ int   srcl[NODES*DEG];                       //  3,712 B
    __shared__ float scf[NODES*DEG];                        //  3,712 B (scores -> alpha -> pool)
    __shared__ float ps[2][NODES];                          //    928 B (row sums per head)
    __shared__ float red[2];
    // total = 159,912 B  (1 block/CU)

    const int g   = blockIdx.x;
    const int tid = threadIdx.x;
    const int w    = tid >> 6;
    const int lane = tid & 63;
    const int l15  = lane & 15;
    const int quad = lane >> 4;
    const int wm   = w >> 2;
    const int wn   = w & 3;

    if (tid < NODES * DEG)
        srcl[tid] = eidx[(size_t)g * NODES * DEG + tid] - g * NODES;

    // A staging: thread -> (row am = t>>3, q8 = t&7); float4 at h[row*256 + kb*32 + q8*4]
    const int am = tid >> 3;
    const int q8 = tid & 7;
    long grow = (long)g * NODES + am;
    if (grow >= NN) grow = NN - 1;                 // rows 116..127 are don't-care
    const float* hrow = h + (size_t)grow * HID + q8 * 4;
    const int aoff = ((q8 >> 1) * 128 + am) * 8 + (q8 & 1) * 4;   // els

    for (int hd = 0; hd < 2; hd++) {
        const size_t wbase = (size_t)hd * 4 * 8 * 4096;   // els

        f4v accq[2][2], acck[2][2], accv[2][2], accs[2][2];
        #pragma unroll
        for (int i = 0; i < 2; i++)
            #pragma unroll
            for (int j = 0; j < 2; j++)
                #pragma unroll
                for (int r = 0; r < 4; r++) {
                    accq[i][j][r] = 0.f; acck[i][j][r] = 0.f;
                    accv[i][j][r] = 0.f; accs[i][j][r] = 0.f;
                }

        // ---- prologue: stage kb=0 into buffer 0 ----
        {
            float4 av = *(const float4*)(hrow);
            #pragma unroll
            for (int j = 0; j < 2; j++) {
                int c = w * 2 + j;                 // 0..31
                int ch = c >> 3, sub = c & 7;
                const unsigned short* src = wt + wbase + ((size_t)(ch * 8 + 0)) * 4096 + sub * 512;
                GLD_LDS16((const char*)src + lane * 16, (char*)stB + c * 1024);
            }
            unsigned short o[4] = { f2bf(av.x), f2bf(av.y), f2bf(av.z), f2bf(av.w) };
            *(uint2*)(stA + aoff) = *(const uint2*)o;
        }
        __syncthreads();

        // ---- pipelined main loop: stage(kb+1) overlaps compute(kb) ----
        int cur = 0;
        for (int kb = 0; kb < 8; kb++) {
            float4 av;
            if (kb < 7) {
                av = *(const float4*)(hrow + (kb + 1) * 32);
                #pragma unroll
                for (int j = 0; j < 2; j++) {
                    int c = w * 2 + j;
                    int ch = c >> 3, sub = c & 7;
                    const unsigned short* src = wt + wbase + ((size_t)(ch * 8 + kb + 1)) * 4096 + sub * 512;
                    GLD_LDS16((const char*)src + lane * 16,
                              (char*)stB + (cur ^ 1) * 32768 + c * 1024);
                }
            }
            const unsigned short* sa = stA + cur * 4096;
            const unsigned short* sb = stB + cur * 16384;
            s8v a0 = *(const s8v*)(sa + (quad * 128 + wm * 32 + l15) * 8);
            s8v a1 = *(const s8v*)(sa + (quad * 128 + wm * 32 + 16 + l15) * 8);
            #pragma unroll
            for (int ch = 0; ch < 4; ch++) {
                s8v b0 = *(const s8v*)(sb + ch * 4096 + (quad * 128 + wn * 32 + l15) * 8);
                s8v b1 = *(const s8v*)(sb + ch * 4096 + (quad * 128 + wn * 32 + 16 + l15) * 8);
                f4v (*acc)[2] = (ch == 0) ? accq : (ch == 1) ? acck : (ch == 2) ? accv : accs;
                acc[0][0] = __builtin_amdgcn_mfma_f32_16x16x32_bf16(a0, b0, acc[0][0], 0, 0, 0);
                acc[0][1] = __builtin_amdgcn_mfma_f32_16x16x32_bf16(a0, b1, acc[0][1], 0, 0, 0);
                acc[1][0] = __builtin_amdgcn_mfma_f32_16x16x32_bf16(a1, b0, acc[1][0], 0, 0, 0);
                acc[1][1] = __builtin_amdgcn_mfma_f32_16x16x32_bf16(a1, b1, acc[1][1], 0, 0, 0);
            }
            if (kb < 7) {
                unsigned short o[4] = { f2bf(av.x), f2bf(av.y), f2bf(av.z), f2bf(av.w) };
                *(uint2*)(stA + (cur ^ 1) * 4096 + aoff) = *(const uint2*)o;
            }
            __syncthreads();
            cur ^= 1;
        }

        // ---- park q, k (row layout, zero-pad cols >= 116) ----
        #pragma unroll
        for (int i = 0; i < 2; i++) {
            #pragma unroll
            for (int j = 0; j < 2; j++) {
                int col = wn * 32 + j * 16 + l15;
                #pragma unroll
                for (int r = 0; r < 4; r++) {
                    int row = wm * 32 + i * 16 + quad * 4 + r;
                    ql[row * RSTR + col] = (col < NODES) ? f2bf(accq[i][j][r]) : 0;
                    kl[row * RSTR + col] = (col < NODES) ? f2bf(acck[i][j][r]) : 0;
                }
            }
        }
        __syncthreads();

        // ---- S = Q.K^T (K=128) ----
        f4v sacc[2][2];
        #pragma unroll
        for (int i = 0; i < 2; i++)
            #pragma unroll
            for (int j = 0; j < 2; j++)
                #pragma unroll
                for (int r = 0; r < 4; r++) sacc[i][j][r] = 0.f;
        #pragma unroll
        for (int ks = 0; ks < 4; ks++) {
            s8v a0 = *(const s8v*)(ql + (wm * 32 + l15) * RSTR + ks * 32 + quad * 8);
            s8v a1 = *(const s8v*)(ql + (wm * 32 + 16 + l15) * RSTR + ks * 32 + quad * 8);
            s8v b0 = *(const s8v*)(kl + (wn * 32 + l15) * RSTR + ks * 32 + quad * 8);
            s8v b1 = *(const s8v*)(kl + (wn * 32 + 16 + l15) * RSTR + ks * 32 + quad * 8);
            sacc[0][0] = __builtin_amdgcn_mfma_f32_16x16x32_bf16(a0, b0, sacc[0][0], 0, 0, 0);
            sacc[0][1] = __builtin_amdgcn_mfma_f32_16x16x32_bf16(a0, b1, sacc[0][1], 0, 0, 0);
            sacc[1][0] = __builtin_amdgcn_mfma_f32_16x16x32_bf16(a1, b0, sacc[1][0], 0, 0, 0);
            sacc[1][1] = __builtin_amdgcn_mfma_f32_16x16x32_bf16(a1, b1, sacc[1][1], 0, 0, 0);
        }
        // selective scatter: exact f32 score for each of the 8 edges per dst row
        #pragma unroll
        for (int i = 0; i < 2; i++) {
            #pragma unroll
            for (int r = 0; r < 4; r++) {
                int row = wm * 32 + i * 16 + quad * 4 + r;
                if (row < NODES) {
                    #pragma unroll
                    for (int j = 0; j < 2; j++) {
                        int col = wn * 32 + j * 16 + l15;
                        #pragma unroll
                        for (int e = 0; e < DEG; e++)
                            if (srcl[row * DEG + e] == col)
                                scf[row * DEG + e] = sacc[i][j][r];
                    }
                }
            }
        }
        __syncthreads();     // scf ready; ql/kl MFMA reads done

        // ---- zero dense-W region (kl) + park V transposed into ql ----
        for (int f = tid; f < 128 * RSTR / 8; f += 1024)
            *(uint4*)(kl + (size_t)f * 8) = make_uint4(0u, 0u, 0u, 0u);
        #pragma unroll
        for (int i = 0; i < 2; i++) {
            #pragma unroll
            for (int j = 0; j < 2; j++) {
                int col = wn * 32 + j * 16 + l15;           // v-dim
                #pragma unroll
                for (int r = 0; r < 4; r++) {
                    int row = wm * 32 + i * 16 + quad * 4 + r;   // src node
                    ql[col * RSTR + row] = (row < NODES) ? f2bf(accv[i][j][r]) : 0;
                }
            }
        }
        __syncthreads();

        // ---- softmax over 8 edges, in place in scf ----
        if (tid < NODES * DEG) {
            float s = scf[tid] * 0.09284766908852594f;   // 1/sqrt(116)
            float m = s;
            m = fmaxf(m, __shfl_xor(m, 1));
            m = fmaxf(m, __shfl_xor(m, 2));
            m = fmaxf(m, __shfl_xor(m, 4));
            float e = __expf(s - m);
            float sum = e;
            sum += __shfl_xor(sum, 1);
            sum += __shfl_xor(sum, 2);
            sum += __shfl_xor(sum, 4);
            scf[tid] = e / sum;                          // own slot only: no race
        }
        __syncthreads();

        // ---- build dense W[dst][src] bf16, duplicates folded in f32 ----
        if (tid < NODES) {
            #pragma unroll
            for (int j = 0; j < DEG; j++) {
                int sj = srcl[tid * DEG + j];
                bool first = true;
                for (int jj = 0; jj < j; jj++) first = first && (srcl[tid * DEG + jj] != sj);
                if (first) {
                    float a = scf[tid * DEG + j];
                    for (int jj = j + 1; jj < DEG; jj++)
                        if (srcl[tid * DEG + jj] == sj) a += scf[tid * DEG + jj];
                    kl[tid * RSTR + sj] = f2bf(a);
                }
            }
        }
        __syncthreads();

        // ---- attn = W @ V (K=128), accumulated onto the skip (s) fragments ----
        #pragma unroll
        for (int ks = 0; ks < 4; ks++) {
            s8v a0 = *(const s8v*)(kl + (wm * 32 + l15) * RSTR + ks * 32 + quad * 8);
            s8v a1 = *(const s8v*)(kl + (wm * 32 + 16 + l15) * RSTR + ks * 32 + quad * 8);
            s8v b0 = *(const s8v*)(ql + (wn * 32 + l15) * RSTR + ks * 32 + quad * 8);
            s8v b1 = *(const s8v*)(ql + (wn * 32 + 16 + l15) * RSTR + ks * 32 + quad * 8);
            accs[0][0] = __builtin_amdgcn_mfma_f32_16x16x32_bf16(a0, b0, accs[0][0], 0, 0, 0);
            accs[0][1] = __builtin_amdgcn_mfma_f32_16x16x32_bf16(a0, b1, accs[0][1], 0, 0, 0);
            accs[1][0] = __builtin_amdgcn_mfma_f32_16x16x32_bf16(a1, b0, accs[1][0], 0, 0, 0);
            accs[1][1] = __builtin_amdgcn_mfma_f32_16x16x32_bf16(a1, b1, accs[1][1], 0, 0, 0);
        }
        __syncthreads();     // W/V^T reads done -> ql reusable

        // ---- h_proj park (row layout, into ql) ----
        #pragma unroll
        for (int i = 0; i < 2; i++) {
            #pragma unroll
            for (int j = 0; j < 2; j++) {
                int col = wn * 32 + j * 16 + l15;
                #pragma unroll
                for (int r = 0; r < 4; r++) {
                    int row = wm * 32 + i * 16 + quad * 4 + r;
                    ql[row * RSTR + col] = f2bf(accs[i][j][r]);
                }
            }
        }
        __syncthreads();

        // ---- row partial sums -> LDS ps[hd] ----
        if (tid < NODES * DEG) {
            const int i   = tid >> 3;
            const int seg = tid & 7;
            float rs = 0.0f;
            #pragma unroll
            for (int t = 0; t < 2; t++) {
                int gi = seg + t * 8;
                if (gi < 15) {                       // cols 116..119 are exact zeros
                    const s8v v8 = *(const s8v*)(ql + i * RSTR + gi * 8);
                    #pragma unroll
                    for (int e = 0; e < 8; e++) rs += bf2f((unsigned short)v8[e]);
                }
            }
            rs += __shfl_xor(rs, 1);
            rs += __shfl_xor(rs, 2);
            rs += __shfl_xor(rs, 4);
            if (seg == 0) ps[hd][i] = rs;
        }
        // ---- head0 h_proj -> global (compact 116 cols); head1 stays in LDS ----
        if (hd == 0) {
            for (int f = tid; f < NODES * 29; f += 1024) {
                int r  = f / 29;
                int gi = f - r * 29;
                *(uint2*)(hp + ((size_t)g * NODES + r) * 116 + gi * 4) =
                    *(const uint2*)(ql + r * RSTR + gi * 4);
            }
        }
        __syncthreads();
    }   // head loop

    // ======== fused per-graph pooling tail (was pool_k2) ========
    if (tid < NODES) scf[tid] = (ps[0][tid] + ps[1][tid]) * (1.0f / DOUT);
    __syncthreads();
    if (tid < 64) {
        float a = scf[tid];
        float b = (tid + 64 < NODES) ? scf[tid + 64] : -1e30f;
        float mm = fmaxf(a, b);
        #pragma unroll
        for (int off = 32; off > 0; off >>= 1) mm = fmaxf(mm, __shfl_down(mm, off));
        if (tid == 0) red[0] = mm;
    }
    __syncthreads();
    if (tid < NODES) scf[tid] = __expf(scf[tid] - red[0]);
    __syncthreads();
    if (tid < 64) {
        float a = scf[tid] + ((tid + 64 < NODES) ? scf[tid + 64] : 0.0f);
        #pragma unroll
        for (int off = 32; off > 0; off >>= 1) a += __shfl_down(a, off);
        if (tid == 0) red[1] = a;
    }
    __syncthreads();
    if (tid < NODES) {
        float al = scf[tid] / red[1];
        scf[tid] = al;
        out_alpha[(size_t)g * NODES + tid] = al;
    }
    __syncthreads();
    for (int f = tid; f < NODES * 58; f += 1024) {   // 58 4-el granules per row
        int r  = f / 58;
        int gi = f - r * 58;
        float al = scf[r];
        float4 o;
        if (gi < 29) {                                // head0 cols 0..115 from hp
            uint2 hv = *(const uint2*)(hp + ((size_t)g * NODES + r) * 116 + gi * 4);
            o = make_float4(al * bf2f((unsigned short)(hv.x & 0xFFFF)),
                            al * bf2f((unsigned short)(hv.x >> 16)),
                            al * bf2f((unsigned short)(hv.y & 0xFFFF)),
                            al * bf2f((unsigned short)(hv.y >> 16)));
        } else {                                      // head1 cols from LDS h_proj
            const unsigned short* hv = ql + r * RSTR + (gi - 29) * 4;
            o = make_float4(al * bf2f(hv[0]), al * bf2f(hv[1]),
                            al * bf2f(hv[2]), al * bf2f(hv[3]));
        }
        *(float4*)(out_hw + ((size_t)g * NODES + r) * DOUT + gi * 4) = o;
    }
}

// ---------------------------------------------------------------------------
extern "C" void kernel_launch(void* const* d_in, const int* in_sizes, int n_in,
                              void* d_out, int out_size, void* d_ws, size_t ws_size,
                              hipStream_t stream)
{
    const float* h    = (const float*)d_in[0];
    const int*   eidx = (const int*)d_in[1];   // row 0 = src
    const float* Wq   = (const float*)d_in[3];
    const float* Wk   = (const float*)d_in[4];
    const float* Wv   = (const float*)d_in[5];
    const float* Ws   = (const float*)d_in[6];

    unsigned short* wt = (unsigned short*)d_ws;        //   262,144 els (0.5 MB)
    unsigned short* hp = wt + (size_t)262144;          // 6,889,472 els (13.8 MB, head0 only)

    float* out_alpha = (float*)d_out;          // [512][116]
    float* out_hw    = out_alpha + NN;         // [59392][232]

    prep_w<<<128, 256, 0, stream>>>(Wq, Wk, Wv, Ws, wt);
    fused_all<<<NGRAPH, 1024, 0, stream>>>(h, wt, eidx, hp, out_alpha, out_hw);
}

// Round 3
// 221.895 us; speedup vs baseline: 1.1128x; 1.1128x over previous
//
#include <hip/hip_runtime.h>

// Problem constants
#define NODES  116
#define HEADS  2
#define DH     116
#define HID    256
#define NGRAPH 512
#define NN     (NGRAPH*NODES)    // 59392
#define DEG    8
#define DOUT   (HEADS*DH)        // 232
#define RSTR   136               // parked-tile row stride (272B, 16B-aligned rows)

typedef short  s8v  __attribute__((ext_vector_type(8)));
typedef float  f4v  __attribute__((ext_vector_type(4)));

static __device__ __forceinline__ float bf2f(unsigned short u) {
    union { unsigned int i; float f; } c; c.i = ((unsigned int)u) << 16; return c.f;
}
static __device__ __forceinline__ unsigned short f2bf(float f) {
    union { float f; unsigned int u; } c; c.f = f;
    unsigned int u = c.u;
    unsigned int r = (u + 0x7FFFu + ((u >> 16) & 1u)) >> 16;   // RNE
    return (unsigned short)r;
}

#define GLD_LDS16(gptr, lptr) \
    __builtin_amdgcn_global_load_lds((const __attribute__((address_space(1))) void*)(gptr), \
                                     (__attribute__((address_space(3))) void*)(lptr), 16, 0, 0)

// ---------------------------------------------------------------------------
// P: wt bf16 [hd(2)][chunk(4)][kb(8)][quad(4)][n(128)][8k]; chunk = Wq,Wk,Wv,Ws
// columns hd*116..+116, transposed, zero-padded n>=116.  (round-0 verified)
// ---------------------------------------------------------------------------
__global__ __launch_bounds__(256) void prep_w(const float* __restrict__ Wq,
                                              const float* __restrict__ Wk,
                                              const float* __restrict__ Wv,
                                              const float* __restrict__ Ws,
                                              unsigned short* __restrict__ wt)
{
    unsigned int f = blockIdx.x * 256 + threadIdx.x;   // granule id < 32768
    unsigned int n    = f & 127;
    unsigned int quad = (f >> 7) & 3;
    unsigned int kb   = (f >> 9) & 7;
    unsigned int ch   = (f >> 12) & 3;
    unsigned int hd   = f >> 14;
    unsigned short o[8] = {0,0,0,0,0,0,0,0};
    if (n < NODES) {
        unsigned int col = hd * DH + n;
        unsigned int k   = kb * 32 + quad * 8;
        const float* W = (ch == 0) ? Wq : (ch == 1) ? Wk : (ch == 2) ? Wv : Ws;
        #pragma unroll
        for (int i = 0; i < 8; i++)
            o[i] = f2bf(W[(size_t)(k + i) * DOUT + col]);
    }
    *(uint4*)(wt + (size_t)f * 8) = *(const uint4*)o;
}

// ---------------------------------------------------------------------------
// K1: one block per GRAPH, 1024 threads = 16 waves.
//   A (h graph tile, bf16) staged ONCE into persistent stA[8 k-slots] (64KB);
//   both heads' GEMMs read it from LDS (h fetched from HBM once per graph).
//   stB (32KB, GEMM-only) and kl (34.8KB, attention-only) share one LDS
//   region (disjoint lifetimes, barrier-separated).
//   Accumulator MFMA uses EXPLICIT per-chunk code (no runtime array select —
//   rule #20: the round-2 pointer-select put all 64 acc f32 in scratch).
//   hd loop force-unrolled -> fully static straight-line code per head.
//   Attention/softmax/W-build/WV/pool tail: round-2 verified forms unchanged.
// ---------------------------------------------------------------------------
__global__ __launch_bounds__(1024) void fused_all(
    const float* __restrict__ h,
    const unsigned short* __restrict__ wt,
    const int* __restrict__ eidx,
    unsigned short* __restrict__ hp,
    float* __restrict__ out_alpha,
    float* __restrict__ out_hw)
{
    __shared__ __align__(16) unsigned short stA[8*4096];    // 65,536 B  A bf16, persists heads
    __shared__ __align__(16) unsigned short xreg[17408];    // 34,816 B  stB (32KB) ∪ kl
    __shared__ __align__(16) unsigned short ql[128*RSTR];   // 34,816 B  q -> v^T -> h_proj
    __shared__ int   srcl[NODES*DEG];                       //  3,712 B
    __shared__ float scf[NODES*DEG];                        //  3,712 B  scores -> alpha -> pool
    __shared__ float ps[2][NODES];                          //    928 B
    __shared__ float red[2];
    // total = 143,528 B

    unsigned short* const stB = xreg;   // [ch(4)][quad(4)][n128][8k] during GEMM
    unsigned short* const kl  = xreg;   // [128][RSTR] k-park / dense-W during attention

    const int g   = blockIdx.x;
    const int tid = threadIdx.x;
    const int w    = tid >> 6;
    const int lane = tid & 63;
    const int l15  = lane & 15;
    const int quad = lane >> 4;
    const int wm   = w >> 2;
    const int wn   = w & 3;

    if (tid < NODES * DEG)
        srcl[tid] = eidx[(size_t)g * NODES * DEG + tid] - g * NODES;

    // ---- A-fill (head-independent): h f32 -> bf16 -> stA[kb], once ----
    // thread -> (row am = t>>3, q8 = t&7); float4 at h[row*256 + kb*32 + q8*4]
    {
        const int am = tid >> 3;
        const int q8 = tid & 7;
        long grow = (long)g * NODES + am;
        if (grow >= NN) grow = NN - 1;             // rows 116..127 are don't-care
        const float* hrow = h + (size_t)grow * HID + q8 * 4;
        const int aoff = ((q8 >> 1) * 128 + am) * 8 + (q8 & 1) * 4;   // els
        float4 a8[8];
        #pragma unroll
        for (int kb = 0; kb < 8; kb++) a8[kb] = *(const float4*)(hrow + kb * 32);
        #pragma unroll
        for (int kb = 0; kb < 8; kb++) {
            unsigned short o[4] = { f2bf(a8[kb].x), f2bf(a8[kb].y),
                                    f2bf(a8[kb].z), f2bf(a8[kb].w) };
            *(uint2*)(stA + kb * 4096 + aoff) = *(const uint2*)o;
        }
    }
    // (first __syncthreads inside the k-loop covers these writes)

    #pragma unroll
    for (int hd = 0; hd < 2; hd++) {
        const size_t wbase = (size_t)hd * 4 * 8 * 4096;   // els

        f4v accq[2][2], acck[2][2], accv[2][2], accs[2][2];
        #pragma unroll
        for (int i = 0; i < 2; i++)
            #pragma unroll
            for (int j = 0; j < 2; j++)
                #pragma unroll
                for (int r = 0; r < 4; r++) {
                    accq[i][j][r] = 0.f; acck[i][j][r] = 0.f;
                    accv[i][j][r] = 0.f; accs[i][j][r] = 0.f;
                }

        // ---- GEMM main loop (B single-buffered; A from persistent stA) ----
        for (int kb = 0; kb < 8; kb++) {
            #pragma unroll
            for (int j = 0; j < 2; j++) {
                int c = w * 2 + j;                 // 0..31
                int ch = c >> 3, sub = c & 7;
                const unsigned short* src = wt + wbase + ((size_t)(ch * 8 + kb)) * 4096 + sub * 512;
                GLD_LDS16((const char*)src + lane * 16, (char*)stB + c * 1024);
            }
            __syncthreads();
            const unsigned short* sa = stA + kb * 4096;
            s8v a0 = *(const s8v*)(sa + (quad * 128 + wm * 32 + l15) * 8);
            s8v a1 = *(const s8v*)(sa + (quad * 128 + wm * 32 + 16 + l15) * 8);
            // explicit per-chunk MFMA: every acc index is a compile-time constant
            #define CHUNK_MFMA(ACC, CH) { \
                s8v b0 = *(const s8v*)(stB + (CH) * 4096 + (quad * 128 + wn * 32 + l15) * 8); \
                s8v b1 = *(const s8v*)(stB + (CH) * 4096 + (quad * 128 + wn * 32 + 16 + l15) * 8); \
                ACC[0][0] = __builtin_amdgcn_mfma_f32_16x16x32_bf16(a0, b0, ACC[0][0], 0, 0, 0); \
                ACC[0][1] = __builtin_amdgcn_mfma_f32_16x16x32_bf16(a0, b1, ACC[0][1], 0, 0, 0); \
                ACC[1][0] = __builtin_amdgcn_mfma_f32_16x16x32_bf16(a1, b0, ACC[1][0], 0, 0, 0); \
                ACC[1][1] = __builtin_amdgcn_mfma_f32_16x16x32_bf16(a1, b1, ACC[1][1], 0, 0, 0); }
            CHUNK_MFMA(accq, 0)
            CHUNK_MFMA(acck, 1)
            CHUNK_MFMA(accv, 2)
            CHUNK_MFMA(accs, 3)
            #undef CHUNK_MFMA
            __syncthreads();
        }

        // ---- park q, k (row layout, zero-pad cols >= 116) ----
        #pragma unroll
        for (int i = 0; i < 2; i++) {
            #pragma unroll
            for (int j = 0; j < 2; j++) {
                int col = wn * 32 + j * 16 + l15;
                #pragma unroll
                for (int r = 0; r < 4; r++) {
                    int row = wm * 32 + i * 16 + quad * 4 + r;
                    ql[row * RSTR + col] = (col < NODES) ? f2bf(accq[i][j][r]) : 0;
                    kl[row * RSTR + col] = (col < NODES) ? f2bf(acck[i][j][r]) : 0;
                }
            }
        }
        __syncthreads();

        // ---- S = Q.K^T (K=128) ----
        f4v sacc[2][2];
        #pragma unroll
        for (int i = 0; i < 2; i++)
            #pragma unroll
            for (int j = 0; j < 2; j++)
                #pragma unroll
                for (int r = 0; r < 4; r++) sacc[i][j][r] = 0.f;
        #pragma unroll
        for (int ks = 0; ks < 4; ks++) {
            s8v a0 = *(const s8v*)(ql + (wm * 32 + l15) * RSTR + ks * 32 + quad * 8);
            s8v a1 = *(const s8v*)(ql + (wm * 32 + 16 + l15) * RSTR + ks * 32 + quad * 8);
            s8v b0 = *(const s8v*)(kl + (wn * 32 + l15) * RSTR + ks * 32 + quad * 8);
            s8v b1 = *(const s8v*)(kl + (wn * 32 + 16 + l15) * RSTR + ks * 32 + quad * 8);
            sacc[0][0] = __builtin_amdgcn_mfma_f32_16x16x32_bf16(a0, b0, sacc[0][0], 0, 0, 0);
            sacc[0][1] = __builtin_amdgcn_mfma_f32_16x16x32_bf16(a0, b1, sacc[0][1], 0, 0, 0);
            sacc[1][0] = __builtin_amdgcn_mfma_f32_16x16x32_bf16(a1, b0, sacc[1][0], 0, 0, 0);
            sacc[1][1] = __builtin_amdgcn_mfma_f32_16x16x32_bf16(a1, b1, sacc[1][1], 0, 0, 0);
        }
        // selective scatter: exact f32 score for each of the 8 edges per dst row
        #pragma unroll
        for (int i = 0; i < 2; i++) {
            #pragma unroll
            for (int r = 0; r < 4; r++) {
                int row = wm * 32 + i * 16 + quad * 4 + r;
                if (row < NODES) {
                    #pragma unroll
                    for (int j = 0; j < 2; j++) {
                        int col = wn * 32 + j * 16 + l15;
                        #pragma unroll
                        for (int e = 0; e < DEG; e++)
                            if (srcl[row * DEG + e] == col)
                                scf[row * DEG + e] = sacc[i][j][r];
                    }
                }
            }
        }
        __syncthreads();     // scf ready; ql/kl MFMA reads done

        // ---- zero dense-W region (kl) + park V transposed into ql ----
        for (int f = tid; f < 128 * RSTR / 8; f += 1024)
            *(uint4*)(kl + (size_t)f * 8) = make_uint4(0u, 0u, 0u, 0u);
        #pragma unroll
        for (int i = 0; i < 2; i++) {
            #pragma unroll
            for (int j = 0; j < 2; j++) {
                int col = wn * 32 + j * 16 + l15;           // v-dim
                #pragma unroll
                for (int r = 0; r < 4; r++) {
                    int row = wm * 32 + i * 16 + quad * 4 + r;   // src node
                    ql[col * RSTR + row] = (row < NODES) ? f2bf(accv[i][j][r]) : 0;
                }
            }
        }
        __syncthreads();

        // ---- softmax over 8 edges, in place in scf ----
        if (tid < NODES * DEG) {
            float s = scf[tid] * 0.09284766908852594f;   // 1/sqrt(116)
            float m = s;
            m = fmaxf(m, __shfl_xor(m, 1));
            m = fmaxf(m, __shfl_xor(m, 2));
            m = fmaxf(m, __shfl_xor(m, 4));
            float e = __expf(s - m);
            float sum = e;
            sum += __shfl_xor(sum, 1);
            sum += __shfl_xor(sum, 2);
            sum += __shfl_xor(sum, 4);
            scf[tid] = e / sum;                          // own slot only: no race
        }
        __syncthreads();

        // ---- build dense W[dst][src] bf16, duplicates folded in f32 ----
        if (tid < NODES) {
            #pragma unroll
            for (int j = 0; j < DEG; j++) {
                int sj = srcl[tid * DEG + j];
                bool first = true;
                for (int jj = 0; jj < j; jj++) first = first && (srcl[tid * DEG + jj] != sj);
                if (first) {
                    float a = scf[tid * DEG + j];
                    for (int jj = j + 1; jj < DEG; jj++)
                        if (srcl[tid * DEG + jj] == sj) a += scf[tid * DEG + jj];
                    kl[tid * RSTR + sj] = f2bf(a);
                }
            }
        }
        __syncthreads();

        // ---- attn = W @ V (K=128), accumulated onto the skip (s) fragments ----
        #pragma unroll
        for (int ks = 0; ks < 4; ks++) {
            s8v a0 = *(const s8v*)(kl + (wm * 32 + l15) * RSTR + ks * 32 + quad * 8);
            s8v a1 = *(const s8v*)(kl + (wm * 32 + 16 + l15) * RSTR + ks * 32 + quad * 8);
            s8v b0 = *(const s8v*)(ql + (wn * 32 + l15) * RSTR + ks * 32 + quad * 8);
            s8v b1 = *(const s8v*)(ql + (wn * 32 + 16 + l15) * RSTR + ks * 32 + quad * 8);
            accs[0][0] = __builtin_amdgcn_mfma_f32_16x16x32_bf16(a0, b0, accs[0][0], 0, 0, 0);
            accs[0][1] = __builtin_amdgcn_mfma_f32_16x16x32_bf16(a0, b1, accs[0][1], 0, 0, 0);
            accs[1][0] = __builtin_amdgcn_mfma_f32_16x16x32_bf16(a1, b0, accs[1][0], 0, 0, 0);
            accs[1][1] = __builtin_amdgcn_mfma_f32_16x16x32_bf16(a1, b1, accs[1][1], 0, 0, 0);
        }
        __syncthreads();     // W/V^T reads done -> ql reusable

        // ---- h_proj park (row layout, into ql) ----
        #pragma unroll
        for (int i = 0; i < 2; i++) {
            #pragma unroll
            for (int j = 0; j < 2; j++) {
                int col = wn * 32 + j * 16 + l15;
                #pragma unroll
                for (int r = 0; r < 4; r++) {
                    int row = wm * 32 + i * 16 + quad * 4 + r;
                    ql[row * RSTR + col] = f2bf(accs[i][j][r]);
                }
            }
        }
        __syncthreads();

        // ---- row partial sums -> LDS ps[hd] ----
        if (tid < NODES * DEG) {
            const int i   = tid >> 3;
            const int seg = tid & 7;
            float rs = 0.0f;
            #pragma unroll
            for (int t = 0; t < 2; t++) {
                int gi = seg + t * 8;
                if (gi < 15) {                       // cols 116..119 are exact zeros
                    const s8v v8 = *(const s8v*)(ql + i * RSTR + gi * 8);
                    #pragma unroll
                    for (int e = 0; e < 8; e++) rs += bf2f((unsigned short)v8[e]);
                }
            }
            rs += __shfl_xor(rs, 1);
            rs += __shfl_xor(rs, 2);
            rs += __shfl_xor(rs, 4);
            if (seg == 0) ps[hd][i] = rs;
        }
        // ---- head0 h_proj -> global (compact 116 cols); head1 stays in LDS ----
        if (hd == 0) {
            for (int f = tid; f < NODES * 29; f += 1024) {
                int r  = f / 29;
                int gi = f - r * 29;
                *(uint2*)(hp + ((size_t)g * NODES + r) * 116 + gi * 4) =
                    *(const uint2*)(ql + r * RSTR + gi * 4);
            }
        }
        __syncthreads();
    }   // head loop

    // ======== fused per-graph pooling tail ========
    if (tid < NODES) scf[tid] = (ps[0][tid] + ps[1][tid]) * (1.0f / DOUT);
    __syncthreads();
    if (tid < 64) {
        float a = scf[tid];
        float b = (tid + 64 < NODES) ? scf[tid + 64] : -1e30f;
        float mm = fmaxf(a, b);
        #pragma unroll
        for (int off = 32; off > 0; off >>= 1) mm = fmaxf(mm, __shfl_down(mm, off));
        if (tid == 0) red[0] = mm;
    }
    __syncthreads();
    if (tid < NODES) scf[tid] = __expf(scf[tid] - red[0]);
    __syncthreads();
    if (tid < 64) {
        float a = scf[tid] + ((tid + 64 < NODES) ? scf[tid + 64] : 0.0f);
        #pragma unroll
        for (int off = 32; off > 0; off >>= 1) a += __shfl_down(a, off);
        if (tid == 0) red[1] = a;
    }
    __syncthreads();
    if (tid < NODES) {
        float al = scf[tid] / red[1];
        scf[tid] = al;
        out_alpha[(size_t)g * NODES + tid] = al;
    }
    __syncthreads();
    for (int f = tid; f < NODES * 58; f += 1024) {   // 58 4-el granules per row
        int r  = f / 58;
        int gi = f - r * 58;
        float al = scf[r];
        float4 o;
        if (gi < 29) {                                // head0 cols 0..115 from hp
            uint2 hv = *(const uint2*)(hp + ((size_t)g * NODES + r) * 116 + gi * 4);
            o = make_float4(al * bf2f((unsigned short)(hv.x & 0xFFFF)),
                            al * bf2f((unsigned short)(hv.x >> 16)),
                            al * bf2f((unsigned short)(hv.y & 0xFFFF)),
                            al * bf2f((unsigned short)(hv.y >> 16)));
        } else {                                      // head1 cols from LDS h_proj
            const unsigned short* hv = ql + r * RSTR + (gi - 29) * 4;
            o = make_float4(al * bf2f(hv[0]), al * bf2f(hv[1]),
                            al * bf2f(hv[2]), al * bf2f(hv[3]));
        }
        *(float4*)(out_hw + ((size_t)g * NODES + r) * DOUT + gi * 4) = o;
    }
}

// ---------------------------------------------------------------------------
extern "C" void kernel_launch(void* const* d_in, const int* in_sizes, int n_in,
                              void* d_out, int out_size, void* d_ws, size_t ws_size,
                              hipStream_t stream)
{
    const float* h    = (const float*)d_in[0];
    const int*   eidx = (const int*)d_in[1];   // row 0 = src
    const float* Wq   = (const float*)d_in[3];
    const float* Wk   = (const float*)d_in[4];
    const float* Wv   = (const float*)d_in[5];
    const float* Ws   = (const float*)d_in[6];

    unsigned short* wt = (unsigned short*)d_ws;        //   262,144 els (0.5 MB)
    unsigned short* hp = wt + (size_t)262144;          // 6,889,472 els (13.8 MB, head0 only)

    float* out_alpha = (float*)d_out;          // [512][116]
    float* out_hw    = out_alpha + NN;         // [59392][232]

    prep_w<<<128, 256, 0, stream>>>(Wq, Wk, Wv, Ws, wt);
    fused_all<<<NGRAPH, 1024, 0, stream>>>(h, wt, eidx, hp, out_alpha, out_hw);
}

// Round 4
// 219.248 us; speedup vs baseline: 1.1262x; 1.0121x over previous
//
#include <hip/hip_runtime.h>

// Problem constants
#define NODES  116
#define HEADS  2
#define DH     116
#define HID    256
#define NGRAPH 512
#define NN     (NGRAPH*NODES)    // 59392
#define DEG    8
#define DOUT   (HEADS*DH)        // 232
#define RSTR   136               // parked-tile row stride (272B, 16B-aligned rows)

typedef short  s8v  __attribute__((ext_vector_type(8)));
typedef float  f4v  __attribute__((ext_vector_type(4)));

static __device__ __forceinline__ float bf2f(unsigned short u) {
    union { unsigned int i; float f; } c; c.i = ((unsigned int)u) << 16; return c.f;
}
static __device__ __forceinline__ unsigned short f2bf(float f) {
    union { float f; unsigned int u; } c; c.f = f;
    unsigned int u = c.u;
    unsigned int r = (u + 0x7FFFu + ((u >> 16) & 1u)) >> 16;   // RNE
    return (unsigned short)r;
}

#define GLD_LDS16(gptr, lptr) \
    __builtin_amdgcn_global_load_lds((const __attribute__((address_space(1))) void*)(gptr), \
                                     (__attribute__((address_space(3))) void*)(lptr), 16, 0, 0)

// ---------------------------------------------------------------------------
// P: wt bf16 [hd(2)][chunk(4)][kb(8)][quad(4)][n(128)][8k]; chunk = Wq,Wk,Wv,Ws
// columns hd*116..+116, transposed, zero-padded n>=116.  (round-0 verified)
// ---------------------------------------------------------------------------
__global__ __launch_bounds__(256) void prep_w(const float* __restrict__ Wq,
                                              const float* __restrict__ Wk,
                                              const float* __restrict__ Wv,
                                              const float* __restrict__ Ws,
                                              unsigned short* __restrict__ wt)
{
    unsigned int f = blockIdx.x * 256 + threadIdx.x;   // granule id < 32768
    unsigned int n    = f & 127;
    unsigned int quad = (f >> 7) & 3;
    unsigned int kb   = (f >> 9) & 7;
    unsigned int ch   = (f >> 12) & 3;
    unsigned int hd   = f >> 14;
    unsigned short o[8] = {0,0,0,0,0,0,0,0};
    if (n < NODES) {
        unsigned int col = hd * DH + n;
        unsigned int k   = kb * 32 + quad * 8;
        const float* W = (ch == 0) ? Wq : (ch == 1) ? Wk : (ch == 2) ? Wv : Ws;
        #pragma unroll
        for (int i = 0; i < 8; i++)
            o[i] = f2bf(W[(size_t)(k + i) * DOUT + col]);
    }
    *(uint4*)(wt + (size_t)f * 8) = *(const uint4*)o;
}

// ---------------------------------------------------------------------------
// K1: one block per GRAPH, 1024 threads = 16 waves.
//   __launch_bounds__(1024, 4): LDS caps us at 1 block/CU = 4 waves/SIMD, so
//   request exactly that -> 128-VGPR budget -> no scratch spill (round 3's
//   default 8-wave target capped VGPRs at 64 and spilled ~26 f32/thread,
//   +53 MB HBM writes).
//   A (h graph tile, bf16) staged ONCE into persistent stA[8 k-slots] (64KB);
//   both heads' GEMMs read it from LDS.
//   B is DOUBLE-BUFFERED (stage kb+1 issued before compute kb, one
//   __syncthreads per k-step — round-2-verified race-free structure), at zero
//   LDS cost: the 64KB B-dbuf overlays the ql+kl region (69.6KB), lifetimes
//   disjoint (B-dbuf only inside the k-loop; ql/kl only after its last
//   barrier; head-1 staging may clobber head-0 h_proj — it's already in hp).
//   Accumulator MFMA uses EXPLICIT per-chunk code (rule #20).
//   Attention/softmax/W-build/WV/pool tail: round-3 verified forms unchanged.
// ---------------------------------------------------------------------------
__global__ __launch_bounds__(1024, 4) void fused_all(
    const float* __restrict__ h,
    const unsigned short* __restrict__ wt,
    const int* __restrict__ eidx,
    unsigned short* __restrict__ hp,
    float* __restrict__ out_alpha,
    float* __restrict__ out_hw)
{
    __shared__ __align__(16) unsigned short stA[8*4096];      // 65,536 B  A bf16, persists heads
    __shared__ __align__(16) unsigned short ovl[2*128*RSTR];  // 69,632 B  B-dbuf ∪ (ql,kl)
    __shared__ int   srcl[NODES*DEG];                         //  3,712 B
    __shared__ float scf[NODES*DEG];                          //  3,712 B  scores -> alpha -> pool
    __shared__ float ps[2][NODES];                            //    928 B
    __shared__ float red[2];
    // total = 143,528 B  (1 block/CU)

    unsigned short* const ql = ovl;                 // [128][RSTR] q -> v^T -> h_proj
    unsigned short* const kl = ovl + 128 * RSTR;    // [128][RSTR] k -> dense W
    // B-dbuf: buf0 = ovl + 0, buf1 = ovl + 16384 (els); each 32 KB

    const int g   = blockIdx.x;
    const int tid = threadIdx.x;
    const int w    = tid >> 6;
    const int lane = tid & 63;
    const int l15  = lane & 15;
    const int quad = lane >> 4;
    const int wm   = w >> 2;
    const int wn   = w & 3;

    if (tid < NODES * DEG)
        srcl[tid] = eidx[(size_t)g * NODES * DEG + tid] - g * NODES;

    // ---- A-fill (head-independent): h f32 -> bf16 -> stA[kb], once ----
    // thread -> (row am = t>>3, q8 = t&7); float4 at h[row*256 + kb*32 + q8*4]
    {
        const int am = tid >> 3;
        const int q8 = tid & 7;
        long grow = (long)g * NODES + am;
        if (grow >= NN) grow = NN - 1;             // rows 116..127 are don't-care
        const float* hrow = h + (size_t)grow * HID + q8 * 4;
        const int aoff = ((q8 >> 1) * 128 + am) * 8 + (q8 & 1) * 4;   // els
        float4 a8[8];
        #pragma unroll
        for (int kb = 0; kb < 8; kb++) a8[kb] = *(const float4*)(hrow + kb * 32);
        #pragma unroll
        for (int kb = 0; kb < 8; kb++) {
            unsigned short o[4] = { f2bf(a8[kb].x), f2bf(a8[kb].y),
                                    f2bf(a8[kb].z), f2bf(a8[kb].w) };
            *(uint2*)(stA + kb * 4096 + aoff) = *(const uint2*)o;
        }
    }
    // (first __syncthreads below covers these writes)

    #pragma unroll
    for (int hd = 0; hd < 2; hd++) {
        const size_t wbase = (size_t)hd * 4 * 8 * 4096;   // els

        f4v accq[2][2], acck[2][2], accv[2][2], accs[2][2];
        #pragma unroll
        for (int i = 0; i < 2; i++)
            #pragma unroll
            for (int j = 0; j < 2; j++)
                #pragma unroll
                for (int r = 0; r < 4; r++) {
                    accq[i][j][r] = 0.f; acck[i][j][r] = 0.f;
                    accv[i][j][r] = 0.f; accs[i][j][r] = 0.f;
                }

        // ---- prologue: stage kb=0 into buf0 ----
        #pragma unroll
        for (int j = 0; j < 2; j++) {
            int c = w * 2 + j;                 // 0..31
            int ch = c >> 3, sub = c & 7;
            const unsigned short* src = wt + wbase + ((size_t)(ch * 8)) * 4096 + sub * 512;
            GLD_LDS16((const char*)src + lane * 16, (char*)ovl + c * 1024);
        }
        __syncthreads();

        // ---- pipelined k-loop: stage(kb+1 -> other buf) before compute(kb) ----
        #pragma unroll
        for (int kb = 0; kb < 8; kb++) {
            const unsigned short* curb = ovl + (kb & 1) * 16384;
            unsigned short* nxtb = ovl + ((kb & 1) ^ 1) * 16384;
            if (kb < 7) {
                #pragma unroll
                for (int j = 0; j < 2; j++) {
                    int c = w * 2 + j;
                    int ch = c >> 3, sub = c & 7;
                    const unsigned short* src = wt + wbase + ((size_t)(ch * 8 + kb + 1)) * 4096 + sub * 512;
                    GLD_LDS16((const char*)src + lane * 16, (char*)nxtb + c * 1024);
                }
            }
            const unsigned short* sa = stA + kb * 4096;
            s8v a0 = *(const s8v*)(sa + (quad * 128 + wm * 32 + l15) * 8);
            s8v a1 = *(const s8v*)(sa + (quad * 128 + wm * 32 + 16 + l15) * 8);
            // explicit per-chunk MFMA: every acc index is a compile-time constant
            #define CHUNK_MFMA(ACC, CH) { \
                s8v b0 = *(const s8v*)(curb + (CH) * 4096 + (quad * 128 + wn * 32 + l15) * 8); \
                s8v b1 = *(const s8v*)(curb + (CH) * 4096 + (quad * 128 + wn * 32 + 16 + l15) * 8); \
                ACC[0][0] = __builtin_amdgcn_mfma_f32_16x16x32_bf16(a0, b0, ACC[0][0], 0, 0, 0); \
                ACC[0][1] = __builtin_amdgcn_mfma_f32_16x16x32_bf16(a0, b1, ACC[0][1], 0, 0, 0); \
                ACC[1][0] = __builtin_amdgcn_mfma_f32_16x16x32_bf16(a1, b0, ACC[1][0], 0, 0, 0); \
                ACC[1][1] = __builtin_amdgcn_mfma_f32_16x16x32_bf16(a1, b1, ACC[1][1], 0, 0, 0); }
            CHUNK_MFMA(accq, 0)
            CHUNK_MFMA(acck, 1)
            CHUNK_MFMA(accv, 2)
            CHUNK_MFMA(accs, 3)
            #undef CHUNK_MFMA
            __syncthreads();
        }
        // k-loop done: B-dbuf dead, ovl region becomes ql/kl

        // ---- park q, k (row layout, zero-pad cols >= 116) ----
        #pragma unroll
        for (int i = 0; i < 2; i++) {
            #pragma unroll
            for (int j = 0; j < 2; j++) {
                int col = wn * 32 + j * 16 + l15;
                #pragma unroll
                for (int r = 0; r < 4; r++) {
                    int row = wm * 32 + i * 16 + quad * 4 + r;
                    ql[row * RSTR + col] = (col < NODES) ? f2bf(accq[i][j][r]) : 0;
                    kl[row * RSTR + col] = (col < NODES) ? f2bf(acck[i][j][r]) : 0;
                }
            }
        }
        __syncthreads();

        // ---- S = Q.K^T (K=128) ----
        f4v sacc[2][2];
        #pragma unroll
        for (int i = 0; i < 2; i++)
            #pragma unroll
            for (int j = 0; j < 2; j++)
                #pragma unroll
                for (int r = 0; r < 4; r++) sacc[i][j][r] = 0.f;
        #pragma unroll
        for (int ks = 0; ks < 4; ks++) {
            s8v a0 = *(const s8v*)(ql + (wm * 32 + l15) * RSTR + ks * 32 + quad * 8);
            s8v a1 = *(const s8v*)(ql + (wm * 32 + 16 + l15) * RSTR + ks * 32 + quad * 8);
            s8v b0 = *(const s8v*)(kl + (wn * 32 + l15) * RSTR + ks * 32 + quad * 8);
            s8v b1 = *(const s8v*)(kl + (wn * 32 + 16 + l15) * RSTR + ks * 32 + quad * 8);
            sacc[0][0] = __builtin_amdgcn_mfma_f32_16x16x32_bf16(a0, b0, sacc[0][0], 0, 0, 0);
            sacc[0][1] = __builtin_amdgcn_mfma_f32_16x16x32_bf16(a0, b1, sacc[0][1], 0, 0, 0);
            sacc[1][0] = __builtin_amdgcn_mfma_f32_16x16x32_bf16(a1, b0, sacc[1][0], 0, 0, 0);
            sacc[1][1] = __builtin_amdgcn_mfma_f32_16x16x32_bf16(a1, b1, sacc[1][1], 0, 0, 0);
        }
        // selective scatter: exact f32 score for each of the 8 edges per dst row
        #pragma unroll
        for (int i = 0; i < 2; i++) {
            #pragma unroll
            for (int r = 0; r < 4; r++) {
                int row = wm * 32 + i * 16 + quad * 4 + r;
                if (row < NODES) {
                    #pragma unroll
                    for (int j = 0; j < 2; j++) {
                        int col = wn * 32 + j * 16 + l15;
                        #pragma unroll
                        for (int e = 0; e < DEG; e++)
                            if (srcl[row * DEG + e] == col)
                                scf[row * DEG + e] = sacc[i][j][r];
                    }
                }
            }
        }
        __syncthreads();     // scf ready; ql/kl MFMA reads done

        // ---- zero dense-W region (kl) + park V transposed into ql ----
        for (int f = tid; f < 128 * RSTR / 8; f += 1024)
            *(uint4*)(kl + (size_t)f * 8) = make_uint4(0u, 0u, 0u, 0u);
        #pragma unroll
        for (int i = 0; i < 2; i++) {
            #pragma unroll
            for (int j = 0; j < 2; j++) {
                int col = wn * 32 + j * 16 + l15;           // v-dim
                #pragma unroll
                for (int r = 0; r < 4; r++) {
                    int row = wm * 32 + i * 16 + quad * 4 + r;   // src node
                    ql[col * RSTR + row] = (row < NODES) ? f2bf(accv[i][j][r]) : 0;
                }
            }
        }
        __syncthreads();

        // ---- softmax over 8 edges, in place in scf ----
        if (tid < NODES * DEG) {
            float s = scf[tid] * 0.09284766908852594f;   // 1/sqrt(116)
            float m = s;
            m = fmaxf(m, __shfl_xor(m, 1));
            m = fmaxf(m, __shfl_xor(m, 2));
            m = fmaxf(m, __shfl_xor(m, 4));
            float e = __expf(s - m);
            float sum = e;
            sum += __shfl_xor(sum, 1);
            sum += __shfl_xor(sum, 2);
            sum += __shfl_xor(sum, 4);
            scf[tid] = e / sum;                          // own slot only: no race
        }
        __syncthreads();

        // ---- build dense W[dst][src] bf16, duplicates folded in f32 ----
        if (tid < NODES) {
            #pragma unroll
            for (int j = 0; j < DEG; j++) {
                int sj = srcl[tid * DEG + j];
                bool first = true;
                for (int jj = 0; jj < j; jj++) first = first && (srcl[tid * DEG + jj] != sj);
                if (first) {
                    float a = scf[tid * DEG + j];
                    for (int jj = j + 1; jj < DEG; jj++)
                        if (srcl[tid * DEG + jj] == sj) a += scf[tid * DEG + jj];
                    kl[tid * RSTR + sj] = f2bf(a);
                }
            }
        }
        __syncthreads();

        // ---- attn = W @ V (K=128), accumulated onto the skip (s) fragments ----
        #pragma unroll
        for (int ks = 0; ks < 4; ks++) {
            s8v a0 = *(const s8v*)(kl + (wm * 32 + l15) * RSTR + ks * 32 + quad * 8);
            s8v a1 = *(const s8v*)(kl + (wm * 32 + 16 + l15) * RSTR + ks * 32 + quad * 8);
            s8v b0 = *(const s8v*)(ql + (wn * 32 + l15) * RSTR + ks * 32 + quad * 8);
            s8v b1 = *(const s8v*)(ql + (wn * 32 + 16 + l15) * RSTR + ks * 32 + quad * 8);
            accs[0][0] = __builtin_amdgcn_mfma_f32_16x16x32_bf16(a0, b0, accs[0][0], 0, 0, 0);
            accs[0][1] = __builtin_amdgcn_mfma_f32_16x16x32_bf16(a0, b1, accs[0][1], 0, 0, 0);
            accs[1][0] = __builtin_amdgcn_mfma_f32_16x16x32_bf16(a1, b0, accs[1][0], 0, 0, 0);
            accs[1][1] = __builtin_amdgcn_mfma_f32_16x16x32_bf16(a1, b1, accs[1][1], 0, 0, 0);
        }
        __syncthreads();     // W/V^T reads done -> ql reusable

        // ---- h_proj park (row layout, into ql) ----
        #pragma unroll
        for (int i = 0; i < 2; i++) {
            #pragma unroll
            for (int j = 0; j < 2; j++) {
                int col = wn * 32 + j * 16 + l15;
                #pragma unroll
                for (int r = 0; r < 4; r++) {
                    int row = wm * 32 + i * 16 + quad * 4 + r;
                    ql[row * RSTR + col] = f2bf(accs[i][j][r]);
                }
            }
        }
        __syncthreads();

        // ---- row partial sums -> LDS ps[hd] ----
        if (tid < NODES * DEG) {
            const int i   = tid >> 3;
            const int seg = tid & 7;
            float rs = 0.0f;
            #pragma unroll
            for (int t = 0; t < 2; t++) {
                int gi = seg + t * 8;
                if (gi < 15) {                       // cols 116..119 are exact zeros
                    const s8v v8 = *(const s8v*)(ql + i * RSTR + gi * 8);
                    #pragma unroll
                    for (int e = 0; e < 8; e++) rs += bf2f((unsigned short)v8[e]);
                }
            }
            rs += __shfl_xor(rs, 1);
            rs += __shfl_xor(rs, 2);
            rs += __shfl_xor(rs, 4);
            if (seg == 0) ps[hd][i] = rs;
        }
        // ---- head0 h_proj -> global (compact 116 cols); head1 stays in LDS ----
        if (hd == 0) {
            for (int f = tid; f < NODES * 29; f += 1024) {
                int r  = f / 29;
                int gi = f - r * 29;
                *(uint2*)(hp + ((size_t)g * NODES + r) * 116 + gi * 4) =
                    *(const uint2*)(ql + r * RSTR + gi * 4);
            }
        }
        __syncthreads();
    }   // head loop

    // ======== fused per-graph pooling tail ========
    if (tid < NODES) scf[tid] = (ps[0][tid] + ps[1][tid]) * (1.0f / DOUT);
    __syncthreads();
    if (tid < 64) {
        float a = scf[tid];
        float b = (tid + 64 < NODES) ? scf[tid + 64] : -1e30f;
        float mm = fmaxf(a, b);
        #pragma unroll
        for (int off = 32; off > 0; off >>= 1) mm = fmaxf(mm, __shfl_down(mm, off));
        if (tid == 0) red[0] = mm;
    }
    __syncthreads();
    if (tid < NODES) scf[tid] = __expf(scf[tid] - red[0]);
    __syncthreads();
    if (tid < 64) {
        float a = scf[tid] + ((tid + 64 < NODES) ? scf[tid + 64] : 0.0f);
        #pragma unroll
        for (int off = 32; off > 0; off >>= 1) a += __shfl_down(a, off);
        if (tid == 0) red[1] = a;
    }
    __syncthreads();
    if (tid < NODES) {
        float al = scf[tid] / red[1];
        scf[tid] = al;
        out_alpha[(size_t)g * NODES + tid] = al;
    }
    __syncthreads();
    for (int f = tid; f < NODES * 58; f += 1024) {   // 58 4-el granules per row
        int r  = f / 58;
        int gi = f - r * 58;
        float al = scf[r];
        float4 o;
        if (gi < 29) {                                // head0 cols 0..115 from hp
            uint2 hv = *(const uint2*)(hp + ((size_t)g * NODES + r) * 116 + gi * 4);
            o = make_float4(al * bf2f((unsigned short)(hv.x & 0xFFFF)),
                            al * bf2f((unsigned short)(hv.x >> 16)),
                            al * bf2f((unsigned short)(hv.y & 0xFFFF)),
                            al * bf2f((unsigned short)(hv.y >> 16)));
        } else {                                      // head1 cols from LDS h_proj
            const unsigned short* hv = ql + r * RSTR + (gi - 29) * 4;
            o = make_float4(al * bf2f(hv[0]), al * bf2f(hv[1]),
                            al * bf2f(hv[2]), al * bf2f(hv[3]));
        }
        *(float4*)(out_hw + ((size_t)g * NODES + r) * DOUT + gi * 4) = o;
    }
}

// ---------------------------------------------------------------------------
extern "C" void kernel_launch(void* const* d_in, const int* in_sizes, int n_in,
                              void* d_out, int out_size, void* d_ws, size_t ws_size,
                              hipStream_t stream)
{
    const float* h    = (const float*)d_in[0];
    const int*   eidx = (const int*)d_in[1];   // row 0 = src
    const float* Wq   = (const float*)d_in[3];
    const float* Wk   = (const float*)d_in[4];
    const float* Wv   = (const float*)d_in[5];
    const float* Ws   = (const float*)d_in[6];

    unsigned short* wt = (unsigned short*)d_ws;        //   262,144 els (0.5 MB)
    unsigned short* hp = wt + (size_t)262144;          // 6,889,472 els (13.8 MB, head0 only)

    float* out_alpha = (float*)d_out;          // [512][116]
    float* out_hw    = out_alpha + NN;         // [59392][232]

    prep_w<<<128, 256, 0, stream>>>(Wq, Wk, Wv, Ws, wt);
    fused_all<<<NGRAPH, 1024, 0, stream>>>(h, wt, eidx, hp, out_alpha, out_hw);
}